// Round 11
// baseline (1221.261 us; speedup 1.0000x reference)
//
#include <hip/hip_runtime.h>
#include <math.h>

#define NT 256
#define NBSPLIT 4
#define NB (16 / NBSPLIT)
#define NSWEEPS 4   // fallback kernel only

__device__ __forceinline__ float fsqrt_(float x) { return __builtin_amdgcn_sqrtf(x); }
__device__ __forceinline__ float frcp_(float x)  { return __builtin_amdgcn_rcpf(x); }
__device__ __forceinline__ float frsq_(float x)  { return __builtin_amdgcn_rsqf(x); }

// ---- shared math: Higham scaled-Newton polar factor (3 scaled + 2 plain) ----
__device__ __forceinline__ void polar3(
    float a00, float a01, float a02,
    float a10, float a11, float a12,
    float a20, float a21, float a22,
    float& x00, float& x01, float& x02,
    float& x10, float& x11, float& x12,
    float& x20, float& x21, float& x22)
{
    float nA = a00 * a00 + a01 * a01 + a02 * a02
             + a10 * a10 + a11 * a11 + a12 * a12
             + a20 * a20 + a21 * a21 + a22 * a22;
    float s0 = frsq_(nA);
    x00 = a00 * s0; x01 = a01 * s0; x02 = a02 * s0;
    x10 = a10 * s0; x11 = a11 * s0; x12 = a12 * s0;
    x20 = a20 * s0; x21 = a21 * s0; x22 = a22 * s0;
    #pragma unroll
    for (int it = 0; it < 3; ++it) {
        float c00 = x11 * x22 - x21 * x12;
        float c01 = x12 * x20 - x10 * x22;
        float c02 = x10 * x21 - x11 * x20;
        float c10 = x02 * x21 - x01 * x22;
        float c11 = x00 * x22 - x02 * x20;
        float c12 = x01 * x20 - x00 * x21;
        float c20 = x01 * x12 - x02 * x11;
        float c21 = x02 * x10 - x00 * x12;
        float c22 = x00 * x11 - x01 * x10;
        float det = x00 * c00 + x01 * c01 + x02 * c02;
        float nX = x00 * x00 + x01 * x01 + x02 * x02
                 + x10 * x10 + x11 * x11 + x12 * x12
                 + x20 * x20 + x21 * x21 + x22 * x22;
        float nC = c00 * c00 + c01 * c01 + c02 * c02
                 + c10 * c10 + c11 * c11 + c12 * c12
                 + c20 * c20 + c21 * c21 + c22 * c22;
        float ratio = nC * frcp_(det * det * nX);
        float mu = fsqrt_(fsqrt_(ratio));
        float f1 = 0.5f * mu;
        float f2 = 0.5f * frcp_(mu * det);
        x00 = f1 * x00 + f2 * c00; x01 = f1 * x01 + f2 * c01; x02 = f1 * x02 + f2 * c02;
        x10 = f1 * x10 + f2 * c10; x11 = f1 * x11 + f2 * c11; x12 = f1 * x12 + f2 * c12;
        x20 = f1 * x20 + f2 * c20; x21 = f1 * x21 + f2 * c21; x22 = f1 * x22 + f2 * c22;
    }
    #pragma unroll
    for (int it = 0; it < 2; ++it) {
        float c00 = x11 * x22 - x21 * x12;
        float c01 = x12 * x20 - x10 * x22;
        float c02 = x10 * x21 - x11 * x20;
        float c10 = x02 * x21 - x01 * x22;
        float c11 = x00 * x22 - x02 * x20;
        float c12 = x01 * x20 - x00 * x21;
        float c20 = x01 * x12 - x02 * x11;
        float c21 = x02 * x10 - x00 * x12;
        float c22 = x00 * x11 - x01 * x10;
        float det = x00 * c00 + x01 * c01 + x02 * c02;
        float f2 = 0.5f * frcp_(det);
        x00 = 0.5f * x00 + f2 * c00; x01 = 0.5f * x01 + f2 * c01; x02 = 0.5f * x02 + f2 * c02;
        x10 = 0.5f * x10 + f2 * c10; x11 = 0.5f * x11 + f2 * c11; x12 = 0.5f * x12 + f2 * c12;
        x20 = 0.5f * x20 + f2 * c20; x21 = 0.5f * x21 + f2 * c21; x22 = 0.5f * x22 + f2 * c22;
    }
}

// ---- det<0 fix: flip LARGEST singular column. R = Q - 2 (Q v1) v1^T ----
// lam1 via deflated quadratic (r10, validated to 1 bf16 ulp); projector
// G = M^2 - (c2-lam1) M + (c0/lam1) I ∝ v1 v1^T.
__device__ __forceinline__ void flipmax3(
    float a00, float a01, float a02,
    float a10, float a11, float a12,
    float a20, float a21, float a22, float detA,
    float& x00, float& x01, float& x02,
    float& x10, float& x11, float& x12,
    float& x20, float& x21, float& x22)
{
    float m00 = a00 * a00 + a10 * a10 + a20 * a20;
    float m01 = a00 * a01 + a10 * a11 + a20 * a21;
    float m02 = a00 * a02 + a10 * a12 + a20 * a22;
    float m11 = a01 * a01 + a11 * a11 + a21 * a21;
    float m12 = a01 * a02 + a11 * a12 + a21 * a22;
    float m22 = a02 * a02 + a12 * a12 + a22 * a22;
    float c2 = m00 + m11 + m22;
    float c1 = m00 * m11 - m01 * m01 + m00 * m22 - m02 * m02
             + m11 * m22 - m12 * m12;
    float c0 = detA * detA;
    float lam3 = c0 * frcp_(c1);
    float ch2 = c2 - lam3;
    float ch1 = c1 - lam3 * ch2;
    float disc = fmaxf(ch2 * ch2 - 4.0f * ch1, 0.0f);
    float lam = 0.5f * (ch2 + fsqrt_(disc));
    float sft = c2 - lam;
    float prd = c0 * frcp_(lam);
    float q00 = m00 * m00 + m01 * m01 + m02 * m02 - sft * m00 + prd;
    float q01 = m00 * m01 + m01 * m11 + m02 * m12 - sft * m01;
    float q02 = m00 * m02 + m01 * m12 + m02 * m22 - sft * m02;
    float q11 = m01 * m01 + m11 * m11 + m12 * m12 - sft * m11 + prd;
    float q12 = m01 * m02 + m11 * m12 + m12 * m22 - sft * m12;
    float q22 = m02 * m02 + m12 * m12 + m22 * m22 - sft * m22 + prd;
    float vx, vy, vz;
    if (q00 >= q11 && q00 >= q22)      { vx = q00; vy = q01; vz = q02; }
    else if (q11 >= q22)               { vx = q01; vy = q11; vz = q12; }
    else                               { vx = q02; vy = q12; vz = q22; }
    float inv = frsq_(vx * vx + vy * vy + vz * vz);
    vx *= inv; vy *= inv; vz *= inv;
    float ux = x00 * vx + x01 * vy + x02 * vz;
    float uy = x10 * vx + x11 * vy + x12 * vz;
    float uz = x20 * vx + x21 * vy + x22 * vz;
    x00 -= 2.0f * ux * vx; x01 -= 2.0f * ux * vy; x02 -= 2.0f * ux * vz;
    x10 -= 2.0f * uy * vx; x11 -= 2.0f * uy * vy; x12 -= 2.0f * uy * vz;
    x20 -= 2.0f * uz * vx; x21 -= 2.0f * uz * vy; x22 -= 2.0f * uz * vz;
}

// maxd==6 main kernel, COMPACTION version (r10 lesson: the inline det<0
// block costs ~18 us structurally — it keeps A live across Newton and
// splits the straight-line body; op count alone explains only ~4 us).
// det<0 lanes push (b<<20|v) to a ws list (wave-aggregated atomic, m20),
// contribute 0 here; arap_fix recomputes them properly. Overflow (idx>=cap)
// lanes fall back to inline flipmax3 — with cap=0 this degenerates to r10.
__global__ __launch_bounds__(NT) void arap_fused6(
    const float* __restrict__ pred,      // (B, 3, n)
    const int*   __restrict__ adj_idx,   // (n, 6)
    const float* __restrict__ adj_w,     // (n, 6)
    const float* __restrict__ tevT,      // (n, 3, 6)
    float* __restrict__ partials,        // (B, nblk_x)
    unsigned* __restrict__ cnt,          // flagged-pair counter
    unsigned* __restrict__ list,         // flagged-pair list
    int cap, int n, int nblk_x)
{
    __shared__ float tvs[18][NT];        // thread-private column, no barriers
    __shared__ float sm[NT / 64][NB];

    const int tid = threadIdx.x;
    const int v = blockIdx.x * NT + tid;
    const bool active = (v < n);
    const int vc = active ? v : 0;
    const int b0 = blockIdx.y * NB;

    int   jo[6];
    float wgt[6];
    {
        const int2* ai = (const int2*)(adj_idx + (size_t)vc * 6);
        int2 q0 = ai[0], q1 = ai[1], q2 = ai[2];
        jo[0] = q0.x; jo[1] = q0.y; jo[2] = q1.x;
        jo[3] = q1.y; jo[4] = q2.x; jo[5] = q2.y;
        const float2* aw = (const float2*)(adj_w + (size_t)vc * 6);
        float2 w0 = aw[0], w1 = aw[1], w2 = aw[2];
        wgt[0] = w0.x; wgt[1] = w0.y; wgt[2] = w1.x;
        wgt[3] = w1.y; wgt[4] = w2.x; wgt[5] = w2.y;
        const float2* tv = (const float2*)(tevT + (size_t)vc * 18);
        #pragma unroll
        for (int i = 0; i < 9; ++i) {
            float2 t = tv[i];
            tvs[2 * i][tid]     = t.x;
            tvs[2 * i + 1][tid] = t.y;
        }
    }

    const int lane = tid & 63, wid = tid >> 6;

    #pragma unroll 1
    for (int bi = 0; bi < NB; ++bi) {
        const float* __restrict__ predb = pred + (size_t)(b0 + bi) * 3 * n;
        const float p0x = predb[vc];
        const float p0y = predb[n + vc];
        const float p0z = predb[2 * n + vc];

        // Pass 1: gather edges (cached for pass 2), A = pred_ev @ (w*tevT^T)
        float ex[6], ey[6], ez[6];
        float a00 = 0.f, a01 = 0.f, a02 = 0.f;
        float a10 = 0.f, a11 = 0.f, a12 = 0.f;
        float a20 = 0.f, a21 = 0.f, a22 = 0.f;
        #pragma unroll
        for (int k = 0; k < 6; ++k) {
            int j = jo[k];
            float exk = predb[j]         - p0x;
            float eyk = predb[n + j]     - p0y;
            float ezk = predb[2 * n + j] - p0z;
            ex[k] = exk; ey[k] = eyk; ez[k] = ezk;
            float t0 = tvs[k][tid], t1 = tvs[6 + k][tid], t2 = tvs[12 + k][tid];
            float w = wgt[k];
            float fx = w * exk, fy = w * eyk, fz = w * ezk;
            a00 += fx * t0; a01 += fx * t1; a02 += fx * t2;
            a10 += fy * t0; a11 += fy * t1; a12 += fy * t2;
            a20 += fz * t0; a21 += fz * t1; a22 += fz * t2;
        }

        float detA = a00 * (a11 * a22 - a21 * a12)
                   - a10 * (a01 * a22 - a21 * a02)
                   + a20 * (a01 * a12 - a11 * a02);

        // defer det<0 lanes to arap_fix (resolve BEFORE Newton so A dies early)
        bool flagged = active && (detA < 0.0f);
        bool pushed = false;
        if (flagged) {
            unsigned idx = atomicAdd(cnt, 1u);   // wave-aggregated (m20)
            if (idx < (unsigned)cap) {
                list[idx] = ((unsigned)(b0 + bi) << 20) | (unsigned)v;
                pushed = true;
            }
        }

        float x00, x01, x02, x10, x11, x12, x20, x21, x22;
        polar3(a00, a01, a02, a10, a11, a12, a20, a21, a22,
               x00, x01, x02, x10, x11, x12, x20, x21, x22);
        if (flagged && !pushed)   // overflow only (cap sized to never hit)
            flipmax3(a00, a01, a02, a10, a11, a12, a20, a21, a22, detA,
                     x00, x01, x02, x10, x11, x12, x20, x21, x22);

        // Pass 2: energy from cached edges
        float nrg = 0.0f;
        #pragma unroll
        for (int k = 0; k < 6; ++k) {
            float t0 = tvs[k][tid], t1 = tvs[6 + k][tid], t2 = tvs[12 + k][tid];
            float q0 = x00 * t0 + x01 * t1 + x02 * t2;
            float q1 = x10 * t0 + x11 * t1 + x12 * t2;
            float q2 = x20 * t0 + x21 * t1 + x22 * t2;
            float dx = ex[k] - q0, dy = ey[k] - q1, dz = ez[k] - q2;
            nrg += wgt[k] * fsqrt_(dx * dx + dy * dy + dz * dz);
        }
        float val = (active && !pushed) ? fminf(nrg, 1.0f) : 0.0f;

        #pragma unroll
        for (int off = 32; off > 0; off >>= 1)
            val += __shfl_down(val, off, 64);
        if (lane == 0) sm[wid][bi] = val;
    }

    __syncthreads();
    if (tid < NB) {
        float s = 0.0f;
        #pragma unroll
        for (int w = 0; w < NT / 64; ++w) s += sm[w][tid];
        partials[(size_t)(b0 + tid) * nblk_x + blockIdx.x] = s;
    }
}

// Deferred det<0 pairs: recompute with polar + largest-column flip.
// ~48k pairs: <1 wave/SIMD, a few us. Data is L2/L3-warm from main kernel.
__global__ __launch_bounds__(NT) void arap_fix(
    const float* __restrict__ pred,
    const int*   __restrict__ adj_idx,
    const float* __restrict__ adj_w,
    const float* __restrict__ tevT,
    const unsigned* __restrict__ list,
    const unsigned* __restrict__ cnt,
    float* __restrict__ extra,           // per-batch energy accumulator
    int n, int cap)
{
    int count = (int)*cnt;
    if (count > cap) count = cap;
    for (int i = blockIdx.x * NT + threadIdx.x; i < count;
         i += gridDim.x * NT) {
        unsigned code = list[i];
        int v = (int)(code & 0xFFFFFu);
        int b = (int)(code >> 20);
        const float* __restrict__ predb = pred + (size_t)b * 3 * n;
        const int*   ai = adj_idx + (size_t)v * 6;
        const float* aw = adj_w  + (size_t)v * 6;
        const float* tv = tevT   + (size_t)v * 18;
        float p0x = predb[v], p0y = predb[n + v], p0z = predb[2 * n + v];

        float ex[6], ey[6], ez[6], tw0[6], tw1[6], tw2[6], wg[6];
        float a00 = 0.f, a01 = 0.f, a02 = 0.f;
        float a10 = 0.f, a11 = 0.f, a12 = 0.f;
        float a20 = 0.f, a21 = 0.f, a22 = 0.f;
        #pragma unroll
        for (int k = 0; k < 6; ++k) {
            int j = ai[k];
            float exk = predb[j]         - p0x;
            float eyk = predb[n + j]     - p0y;
            float ezk = predb[2 * n + j] - p0z;
            ex[k] = exk; ey[k] = eyk; ez[k] = ezk;
            float t0 = tv[k], t1 = tv[6 + k], t2 = tv[12 + k];
            tw0[k] = t0; tw1[k] = t1; tw2[k] = t2;
            float w = aw[k]; wg[k] = w;
            float fx = w * exk, fy = w * eyk, fz = w * ezk;
            a00 += fx * t0; a01 += fx * t1; a02 += fx * t2;
            a10 += fy * t0; a11 += fy * t1; a12 += fy * t2;
            a20 += fz * t0; a21 += fz * t1; a22 += fz * t2;
        }
        float detA = a00 * (a11 * a22 - a21 * a12)
                   - a10 * (a01 * a22 - a21 * a02)
                   + a20 * (a01 * a12 - a11 * a02);
        float x00, x01, x02, x10, x11, x12, x20, x21, x22;
        polar3(a00, a01, a02, a10, a11, a12, a20, a21, a22,
               x00, x01, x02, x10, x11, x12, x20, x21, x22);
        flipmax3(a00, a01, a02, a10, a11, a12, a20, a21, a22, detA,
                 x00, x01, x02, x10, x11, x12, x20, x21, x22);
        float nrg = 0.0f;
        #pragma unroll
        for (int k = 0; k < 6; ++k) {
            float q0 = x00 * tw0[k] + x01 * tw1[k] + x02 * tw2[k];
            float q1 = x10 * tw0[k] + x11 * tw1[k] + x12 * tw2[k];
            float q2 = x20 * tw0[k] + x21 * tw1[k] + x22 * tw2[k];
            float dx = ex[k] - q0, dy = ey[k] - q1, dz = ez[k] - q2;
            nrg += wg[k] * fsqrt_(dx * dx + dy * dy + dz * dz);
        }
        atomicAdd(&extra[b], fminf(nrg, 1.0f));
    }
}

__global__ __launch_bounds__(NT) void arap_reduce2(
    const float* __restrict__ partials, const float* __restrict__ extra,
    float* __restrict__ out, int nblk_x, float inv_n)
{
    int b = blockIdx.x;
    float val = 0.0f;
    for (int i = threadIdx.x; i < nblk_x; i += NT)
        val += partials[(size_t)b * nblk_x + i];
    for (int off = 32; off > 0; off >>= 1)
        val += __shfl_down(val, off, 64);
    __shared__ float smf[NT / 64];
    int lane = threadIdx.x & 63, wid = threadIdx.x >> 6;
    if (lane == 0) smf[wid] = val;
    __syncthreads();
    if (threadIdx.x == 0)
        out[b] = (smf[0] + smf[1] + smf[2] + smf[3] + extra[b]) * inv_n;
}

// ---------------- generic fallback (Jacobi path, unchanged) ----------------
__device__ __forceinline__ void jrot(float& app, float& aqq, float& apq,
                                     float& arp, float& arq,
                                     float& vp0, float& vp1, float& vp2,
                                     float& vq0, float& vq1, float& vq2)
{
    float a = apq;
    float scale = fabsf(app) + fabsf(aqq);
    if (fabsf(a) > 1e-12f * scale + 1e-35f) {
        float h = aqq - app;
        float r = fsqrt_(fmaf(h, h, 4.0f * a * a));
        float den = fabsf(h) + r;
        float t2a = (h >= 0.0f) ? 2.0f * a : -2.0f * a;
        float t = t2a * frcp_(den);
        float c = frsq_(fmaf(t, t, 1.0f));
        float s = t * c;
        app -= t * a;
        aqq += t * a;
        apq = 0.0f;
        float rp = arp, rq = arq;
        arp = c * rp - s * rq;
        arq = s * rp + c * rq;
        float x, y;
        x = vp0; y = vq0; vp0 = c * x - s * y; vq0 = s * x + c * y;
        x = vp1; y = vq1; vp1 = c * x - s * y; vq1 = s * x + c * y;
        x = vp2; y = vq2; vp2 = c * x - s * y; vq2 = s * x + c * y;
    }
}

__global__ __launch_bounds__(NT) void arap_main(
    const float* __restrict__ pred, const int* __restrict__ adj_idx,
    const float* __restrict__ adj_w, const float* __restrict__ tevT,
    const float* __restrict__ tevw, float* __restrict__ partials,
    int n, int maxd, int nblk_x)
{
    const int b = blockIdx.y;
    const float* __restrict__ predb = pred + (size_t)b * 3 * n;
    float local = 0.0f;

    for (int v = blockIdx.x * NT + threadIdx.x; v < n; v += nblk_x * NT) {
        const float p0x = predb[v];
        const float p0y = predb[n + v];
        const float p0z = predb[2 * n + v];

        float a00 = 0.f, a01 = 0.f, a02 = 0.f;
        float a10 = 0.f, a11 = 0.f, a12 = 0.f;
        float a20 = 0.f, a21 = 0.f, a22 = 0.f;
        for (int k = 0; k < maxd; ++k) {
            int j = adj_idx[v * maxd + k];
            float ex = predb[j] - p0x;
            float ey = predb[n + j] - p0y;
            float ez = predb[2 * n + j] - p0z;
            const float* tw = tevw + ((size_t)v * maxd + k) * 3;
            float t0 = tw[0], t1 = tw[1], t2 = tw[2];
            a00 += ex * t0; a01 += ex * t1; a02 += ex * t2;
            a10 += ey * t0; a11 += ey * t1; a12 += ey * t2;
            a20 += ez * t0; a21 += ez * t1; a22 += ez * t2;
        }
        const float stab = 1000.0f;
        a00 *= stab; a01 *= stab; a02 *= stab;
        a10 *= stab; a11 *= stab; a12 *= stab;
        a20 *= stab; a21 *= stab; a22 *= stab;

        float m00 = a00 * a00 + a10 * a10 + a20 * a20;
        float m01 = a00 * a01 + a10 * a11 + a20 * a21;
        float m02 = a00 * a02 + a10 * a12 + a20 * a22;
        float m11 = a01 * a01 + a11 * a11 + a21 * a21;
        float m12 = a01 * a02 + a11 * a12 + a21 * a22;
        float m22 = a02 * a02 + a12 * a12 + a22 * a22;

        float v00 = 1.f, v01 = 0.f, v02 = 0.f;
        float v10 = 0.f, v11 = 1.f, v12 = 0.f;
        float v20 = 0.f, v21 = 0.f, v22 = 1.f;
        #pragma unroll
        for (int sweep = 0; sweep < NSWEEPS; ++sweep) {
            jrot(m00, m11, m01, m02, m12, v00, v10, v20, v01, v11, v21);
            jrot(m00, m22, m02, m01, m12, v00, v10, v20, v02, v12, v22);
            jrot(m11, m22, m12, m01, m02, v01, v11, v21, v02, v12, v22);
        }

        float is0 = frsq_(fmaxf(m00, 1e-6f));
        float is1 = frsq_(fmaxf(m11, 1e-6f));
        float is2 = frsq_(fmaxf(m22, 1e-6f));
        float detA = a00 * (a11 * a22 - a21 * a12)
                   - a10 * (a01 * a22 - a21 * a02)
                   + a20 * (a01 * a12 - a11 * a02);
        float dd = detA * is0 * is1 * is2;
        bool c2 = (m22 >= m00) && (m22 >= m11);
        bool c1 = !c2 && (m11 >= m00);
        bool c0 = !c2 && !c1;
        is0 = c0 ? is0 * dd : is0;
        is1 = c1 ? is1 * dd : is1;
        is2 = c2 ? is2 * dd : is2;

        float w00 = is0 * v00 * v00 + is1 * v01 * v01 + is2 * v02 * v02;
        float w01 = is0 * v00 * v10 + is1 * v01 * v11 + is2 * v02 * v12;
        float w02 = is0 * v00 * v20 + is1 * v01 * v21 + is2 * v02 * v22;
        float w11 = is0 * v10 * v10 + is1 * v11 * v11 + is2 * v12 * v12;
        float w12 = is0 * v10 * v20 + is1 * v11 * v21 + is2 * v12 * v22;
        float w22 = is0 * v20 * v20 + is1 * v21 * v21 + is2 * v22 * v22;

        float r00 = a00 * w00 + a01 * w01 + a02 * w02;
        float r01 = a00 * w01 + a01 * w11 + a02 * w12;
        float r02 = a00 * w02 + a01 * w12 + a02 * w22;
        float r10 = a10 * w00 + a11 * w01 + a12 * w02;
        float r11 = a10 * w01 + a11 * w11 + a12 * w12;
        float r12 = a10 * w02 + a11 * w12 + a12 * w22;
        float r20 = a20 * w00 + a21 * w01 + a22 * w02;
        float r21 = a20 * w01 + a21 * w11 + a22 * w12;
        float r22 = a20 * w02 + a21 * w12 + a22 * w22;

        float nrg = 0.0f;
        const float* tvb = tevT + (size_t)v * 3 * maxd;
        for (int k = 0; k < maxd; ++k) {
            int j = adj_idx[v * maxd + k];
            float w = adj_w[v * maxd + k];
            float ex = predb[j] - p0x;
            float ey = predb[n + j] - p0y;
            float ez = predb[2 * n + j] - p0z;
            float tv0 = tvb[k];
            float tv1 = tvb[maxd + k];
            float tv2 = tvb[2 * maxd + k];
            float q0 = r00 * tv0 + r01 * tv1 + r02 * tv2;
            float q1 = r10 * tv0 + r11 * tv1 + r12 * tv2;
            float q2 = r20 * tv0 + r21 * tv1 + r22 * tv2;
            float dx = ex - q0, dy = ey - q1, dz = ez - q2;
            nrg += w * fsqrt_(dx * dx + dy * dy + dz * dz);
        }
        local += fminf(nrg, 1.0f);
    }

    float val = local;
    for (int off = 32; off > 0; off >>= 1)
        val += __shfl_down(val, off, 64);
    __shared__ float smf[NT / 64];
    int lane = threadIdx.x & 63, wid = threadIdx.x >> 6;
    if (lane == 0) smf[wid] = val;
    __syncthreads();
    if (threadIdx.x == 0)
        partials[(size_t)b * nblk_x + blockIdx.x] = smf[0] + smf[1] + smf[2] + smf[3];
}

__global__ __launch_bounds__(NT) void arap_reduce(
    const float* __restrict__ partials, float* __restrict__ out,
    int nblk_x, float inv_n)
{
    int b = blockIdx.x;
    float val = 0.0f;
    for (int i = threadIdx.x; i < nblk_x; i += NT)
        val += partials[(size_t)b * nblk_x + i];
    for (int off = 32; off > 0; off >>= 1)
        val += __shfl_down(val, off, 64);
    __shared__ float smf[NT / 64];
    int lane = threadIdx.x & 63, wid = threadIdx.x >> 6;
    if (lane == 0) smf[wid] = val;
    __syncthreads();
    if (threadIdx.x == 0)
        out[b] = (smf[0] + smf[1] + smf[2] + smf[3]) * inv_n;
}

extern "C" void kernel_launch(void* const* d_in, const int* in_sizes, int n_in,
                              void* d_out, int out_size, void* d_ws, size_t ws_size,
                              hipStream_t stream)
{
    const float* pred    = (const float*)d_in[0];
    const int*   adj_idx = (const int*)d_in[1];
    const float* adj_w   = (const float*)d_in[2];
    const float* tevT    = (const float*)d_in[3];
    const float* tevw    = (const float*)d_in[4];
    float* out = (float*)d_out;

    const int B = 16;
    const int n = in_sizes[0] / (3 * B);
    const int maxd = in_sizes[1] / n;

    int nblk = (n + NT - 1) / NT;
    int P = B * nblk;                       // partials floats
    long long ws_floats = (long long)(ws_size / sizeof(float));
    float* partials = (float*)d_ws;

    if (maxd == 6 && n < (1 << 20) && ws_floats >= P + 18) {
        // ws layout: [0,P) partials | [P,P+16) extra | [P+16] counter | pad | list
        float*    extra = partials + P;
        unsigned* cnt   = (unsigned*)(partials + P + 16);
        unsigned* list  = (unsigned*)(partials + P + 18);
        long long capll = ws_floats - P - 18;
        int cap = (capll > 0x7FFFFFFFLL) ? 0x7FFFFFFF : (int)capll;

        hipMemsetAsync(extra, 0, 18 * sizeof(float), stream);  // extra+cnt+pad
        dim3 grid(nblk, NBSPLIT);
        arap_fused6<<<grid, NT, 0, stream>>>(pred, adj_idx, adj_w, tevT,
                                             partials, cnt, list, cap, n, nblk);
        arap_fix<<<256, NT, 0, stream>>>(pred, adj_idx, adj_w, tevT,
                                         list, cnt, extra, n, cap);
        arap_reduce2<<<B, NT, 0, stream>>>(partials, extra, out, nblk,
                                           1.0f / (float)n);
    } else {
        int nblk_x = nblk;
        if ((long long)nblk_x * B > ws_floats) nblk_x = (int)(ws_floats / B);
        if (nblk_x < 1) nblk_x = 1;
        dim3 grid(nblk_x, B);
        arap_main<<<grid, NT, 0, stream>>>(pred, adj_idx, adj_w, tevT, tevw,
                                           partials, n, maxd, nblk_x);
        arap_reduce<<<B, NT, 0, stream>>>(partials, out, nblk_x,
                                          1.0f / (float)n);
    }
}

// Round 12
// 50.388 us; speedup vs baseline: 24.2369x; 24.2369x over previous
//
#include <hip/hip_runtime.h>
#include <math.h>

#define NT 256
#define NBSPLIT 4
#define NB (16 / NBSPLIT)
#define NSWEEPS 4   // fallback kernel only

__device__ __forceinline__ float fsqrt_(float x) { return __builtin_amdgcn_sqrtf(x); }
__device__ __forceinline__ float frcp_(float x)  { return __builtin_amdgcn_rcpf(x); }
__device__ __forceinline__ float frsq_(float x)  { return __builtin_amdgcn_rsqf(x); }

// maxd==6 specialized: POLAR-NEWTON + BRANCHLESS always-on argmax flip.
// History of the det<0 correction (reference flips the LARGEST singular
// column when det(A)<0 — ~6% of pairs):
//   r8: ignored -> mean bias, absmax 98% of threshold.
//   r10: inline under `if(detA<0)` -> +18us STRUCTURAL (A+M live across
//        Newton, body split) though op count explains only ~4us.
//   r11: compaction + second kernel -> 1221us: ~100k per-lane float atomics
//        to 16 addresses (0.9ms serialized) + 25k wave atomics to one
//        counter (0.25ms). Global atomics to few addresses are a dead end.
//   r12 (this): v1 = argmax eigvec of M=A^T A depends only on M,detA — both
//        known BEFORE Newton. Compute v1 + s=(detA<0?2:0) early (M dies),
//        polar3 (A dies), then X -= s*(X v1) v1^T unconditionally. No
//        branch, no atomics, only v1+s (4 regs) live across Newton.
// lam1 via deflated quadratic (lam3~c0/c1 quartically small; r9/r10
// validated to 1 bf16 ulp). Degenerate corners (A~0): NaN -> fminf(NaN,1)=1,
// error <= 2/n. NO launch_bounds min-waves pin (r4/r5: catastrophic spill).
__global__ __launch_bounds__(NT) void arap_fused6(
    const float* __restrict__ pred,      // (B, 3, n)
    const int*   __restrict__ adj_idx,   // (n, 6)
    const float* __restrict__ adj_w,     // (n, 6)
    const float* __restrict__ tevT,      // (n, 3, 6)
    float* __restrict__ partials,        // (B, nblk_x)
    int n, int nblk_x)
{
    __shared__ float tvs[18][NT];        // thread-private column, no barriers
    __shared__ float sm[NT / 64][NB];

    const int tid = threadIdx.x;
    const int v = blockIdx.x * NT + tid;
    const bool active = (v < n);
    const int vc = active ? v : 0;
    const int b0 = blockIdx.y * NB;

    int   jo[6];
    float wgt[6];
    {
        const int2* ai = (const int2*)(adj_idx + (size_t)vc * 6);
        int2 q0 = ai[0], q1 = ai[1], q2 = ai[2];
        jo[0] = q0.x; jo[1] = q0.y; jo[2] = q1.x;
        jo[3] = q1.y; jo[4] = q2.x; jo[5] = q2.y;
        const float2* aw = (const float2*)(adj_w + (size_t)vc * 6);
        float2 w0 = aw[0], w1 = aw[1], w2 = aw[2];
        wgt[0] = w0.x; wgt[1] = w0.y; wgt[2] = w1.x;
        wgt[3] = w1.y; wgt[4] = w2.x; wgt[5] = w2.y;
        const float2* tv = (const float2*)(tevT + (size_t)vc * 18);
        #pragma unroll
        for (int i = 0; i < 9; ++i) {
            float2 t = tv[i];
            tvs[2 * i][tid]     = t.x;
            tvs[2 * i + 1][tid] = t.y;
        }
    }

    const int lane = tid & 63, wid = tid >> 6;

    #pragma unroll 1
    for (int bi = 0; bi < NB; ++bi) {
        const float* __restrict__ predb = pred + (size_t)(b0 + bi) * 3 * n;
        const float p0x = predb[vc];
        const float p0y = predb[n + vc];
        const float p0z = predb[2 * n + vc];

        // Pass 1: gather edges (cached for pass 2), A = pred_ev @ (w*tevT^T)
        float ex[6], ey[6], ez[6];
        float a00 = 0.f, a01 = 0.f, a02 = 0.f;
        float a10 = 0.f, a11 = 0.f, a12 = 0.f;
        float a20 = 0.f, a21 = 0.f, a22 = 0.f;
        #pragma unroll
        for (int k = 0; k < 6; ++k) {
            int j = jo[k];
            float exk = predb[j]         - p0x;
            float eyk = predb[n + j]     - p0y;
            float ezk = predb[2 * n + j] - p0z;
            ex[k] = exk; ey[k] = eyk; ez[k] = ezk;
            float t0 = tvs[k][tid], t1 = tvs[6 + k][tid], t2 = tvs[12 + k][tid];
            float w = wgt[k];
            float fx = w * exk, fy = w * eyk, fz = w * ezk;
            a00 += fx * t0; a01 += fx * t1; a02 += fx * t2;
            a10 += fy * t0; a11 += fy * t1; a12 += fy * t2;
            a20 += fz * t0; a21 += fz * t1; a22 += fz * t2;
        }

        float detA = a00 * (a11 * a22 - a21 * a12)
                   - a10 * (a01 * a22 - a21 * a02)
                   + a20 * (a01 * a12 - a11 * a02);

        // ---- hoisted flip precompute: v1 (argmax eigvec of M) + s, BEFORE
        // Newton so M dies here and only {v1, s} cross the Newton section ----
        float vx, vy, vz, s;
        {
            float m00 = a00 * a00 + a10 * a10 + a20 * a20;
            float m01 = a00 * a01 + a10 * a11 + a20 * a21;
            float m02 = a00 * a02 + a10 * a12 + a20 * a22;
            float m11 = a01 * a01 + a11 * a11 + a21 * a21;
            float m12 = a01 * a02 + a11 * a12 + a21 * a22;
            float m22 = a02 * a02 + a12 * a12 + a22 * a22;
            float c2s = m00 + m11 + m22;
            float c1s = m00 * m11 - m01 * m01 + m00 * m22 - m02 * m02
                      + m11 * m22 - m12 * m12;
            float c0s = detA * detA;
            float lam3 = c0s * frcp_(c1s);
            float ch2 = c2s - lam3;
            float ch1 = c1s - lam3 * ch2;
            float disc = fmaxf(ch2 * ch2 - 4.0f * ch1, 0.0f);
            float lam = 0.5f * (ch2 + fsqrt_(disc));
            // G = M^2 - (c2-lam) M + (c0/lam) I  ∝  v1 v1^T
            float sft = c2s - lam;
            float prd = c0s * frcp_(lam);
            float q00 = m00 * m00 + m01 * m01 + m02 * m02 - sft * m00 + prd;
            float q01 = m00 * m01 + m01 * m11 + m02 * m12 - sft * m01;
            float q02 = m00 * m02 + m01 * m12 + m02 * m22 - sft * m02;
            float q11 = m01 * m01 + m11 * m11 + m12 * m12 - sft * m11 + prd;
            float q12 = m01 * m02 + m11 * m12 + m12 * m22 - sft * m12;
            float q22 = m02 * m02 + m12 * m12 + m22 * m22 - sft * m22 + prd;
            if (q00 >= q11 && q00 >= q22)      { vx = q00; vy = q01; vz = q02; }
            else if (q11 >= q22)               { vx = q01; vy = q11; vz = q12; }
            else                               { vx = q02; vy = q12; vz = q22; }
            float inv = frsq_(fmaxf(vx * vx + vy * vy + vz * vz, 1e-30f));
            vx *= inv; vy *= inv; vz *= inv;
            s = (detA < 0.0f) ? 2.0f : 0.0f;
        }

        // ---- Higham scaled Newton polar: X0 = A/||A||F (A dies here) ----
        float nA = a00 * a00 + a01 * a01 + a02 * a02
                 + a10 * a10 + a11 * a11 + a12 * a12
                 + a20 * a20 + a21 * a21 + a22 * a22;
        float s0 = frsq_(nA);
        float x00 = a00 * s0, x01 = a01 * s0, x02 = a02 * s0;
        float x10 = a10 * s0, x11 = a11 * s0, x12 = a12 * s0;
        float x20 = a20 * s0, x21 = a21 * s0, x22 = a22 * s0;

        #pragma unroll
        for (int it = 0; it < 3; ++it) {
            float c00 = x11 * x22 - x21 * x12;
            float c01 = x12 * x20 - x10 * x22;
            float c02 = x10 * x21 - x11 * x20;
            float c10 = x02 * x21 - x01 * x22;
            float c11 = x00 * x22 - x02 * x20;
            float c12 = x01 * x20 - x00 * x21;
            float c20 = x01 * x12 - x02 * x11;
            float c21 = x02 * x10 - x00 * x12;
            float c22 = x00 * x11 - x01 * x10;
            float det = x00 * c00 + x01 * c01 + x02 * c02;
            float nX = x00 * x00 + x01 * x01 + x02 * x02
                     + x10 * x10 + x11 * x11 + x12 * x12
                     + x20 * x20 + x21 * x21 + x22 * x22;
            float nC = c00 * c00 + c01 * c01 + c02 * c02
                     + c10 * c10 + c11 * c11 + c12 * c12
                     + c20 * c20 + c21 * c21 + c22 * c22;
            float ratio = nC * frcp_(det * det * nX);
            float mu = fsqrt_(fsqrt_(ratio));
            float f1 = 0.5f * mu;
            float f2 = 0.5f * frcp_(mu * det);
            x00 = f1 * x00 + f2 * c00;
            x01 = f1 * x01 + f2 * c01;
            x02 = f1 * x02 + f2 * c02;
            x10 = f1 * x10 + f2 * c10;
            x11 = f1 * x11 + f2 * c11;
            x12 = f1 * x12 + f2 * c12;
            x20 = f1 * x20 + f2 * c20;
            x21 = f1 * x21 + f2 * c21;
            x22 = f1 * x22 + f2 * c22;
        }
        #pragma unroll
        for (int it = 0; it < 2; ++it) {
            float c00 = x11 * x22 - x21 * x12;
            float c01 = x12 * x20 - x10 * x22;
            float c02 = x10 * x21 - x11 * x20;
            float c10 = x02 * x21 - x01 * x22;
            float c11 = x00 * x22 - x02 * x20;
            float c12 = x01 * x20 - x00 * x21;
            float c20 = x01 * x12 - x02 * x11;
            float c21 = x02 * x10 - x00 * x12;
            float c22 = x00 * x11 - x01 * x10;
            float det = x00 * c00 + x01 * c01 + x02 * c02;
            float f2 = 0.5f * frcp_(det);
            x00 = 0.5f * x00 + f2 * c00;
            x01 = 0.5f * x01 + f2 * c01;
            x02 = 0.5f * x02 + f2 * c02;
            x10 = 0.5f * x10 + f2 * c10;
            x11 = 0.5f * x11 + f2 * c11;
            x12 = 0.5f * x12 + f2 * c12;
            x20 = 0.5f * x20 + f2 * c20;
            x21 = 0.5f * x21 + f2 * c21;
            x22 = 0.5f * x22 + f2 * c22;
        }

        // ---- branchless flip: X -= s * (X v1) v1^T  (s = 0 or 2) ----
        float ux = x00 * vx + x01 * vy + x02 * vz;
        float uy = x10 * vx + x11 * vy + x12 * vz;
        float uz = x20 * vx + x21 * vy + x22 * vz;
        ux *= s; uy *= s; uz *= s;
        x00 -= ux * vx; x01 -= ux * vy; x02 -= ux * vz;
        x10 -= uy * vx; x11 -= uy * vy; x12 -= uy * vz;
        x20 -= uz * vx; x21 -= uz * vy; x22 -= uz * vz;

        // Pass 2: energy from cached edges
        float nrg = 0.0f;
        #pragma unroll
        for (int k = 0; k < 6; ++k) {
            float t0 = tvs[k][tid], t1 = tvs[6 + k][tid], t2 = tvs[12 + k][tid];
            float q0 = x00 * t0 + x01 * t1 + x02 * t2;
            float q1 = x10 * t0 + x11 * t1 + x12 * t2;
            float q2 = x20 * t0 + x21 * t1 + x22 * t2;
            float dx = ex[k] - q0, dy = ey[k] - q1, dz = ez[k] - q2;
            nrg += wgt[k] * fsqrt_(dx * dx + dy * dy + dz * dz);
        }
        float val = active ? fminf(nrg, 1.0f) : 0.0f;

        #pragma unroll
        for (int off = 32; off > 0; off >>= 1)
            val += __shfl_down(val, off, 64);
        if (lane == 0) sm[wid][bi] = val;
    }

    __syncthreads();
    if (tid < NB) {
        float sacc = 0.0f;
        #pragma unroll
        for (int w = 0; w < NT / 64; ++w) sacc += sm[w][tid];
        partials[(size_t)(b0 + tid) * nblk_x + blockIdx.x] = sacc;
    }
}

// ---------------- generic fallback (Jacobi path) ----------------
__device__ __forceinline__ void jrot(float& app, float& aqq, float& apq,
                                     float& arp, float& arq,
                                     float& vp0, float& vp1, float& vp2,
                                     float& vq0, float& vq1, float& vq2)
{
    float a = apq;
    float scale = fabsf(app) + fabsf(aqq);
    if (fabsf(a) > 1e-12f * scale + 1e-35f) {
        float h = aqq - app;
        float r = fsqrt_(fmaf(h, h, 4.0f * a * a));
        float den = fabsf(h) + r;
        float t2a = (h >= 0.0f) ? 2.0f * a : -2.0f * a;
        float t = t2a * frcp_(den);
        float c = frsq_(fmaf(t, t, 1.0f));
        float s = t * c;
        app -= t * a;
        aqq += t * a;
        apq = 0.0f;
        float rp = arp, rq = arq;
        arp = c * rp - s * rq;
        arq = s * rp + c * rq;
        float x, y;
        x = vp0; y = vq0; vp0 = c * x - s * y; vq0 = s * x + c * y;
        x = vp1; y = vq1; vp1 = c * x - s * y; vq1 = s * x + c * y;
        x = vp2; y = vq2; vp2 = c * x - s * y; vq2 = s * x + c * y;
    }
}

__global__ __launch_bounds__(NT) void arap_main(
    const float* __restrict__ pred, const int* __restrict__ adj_idx,
    const float* __restrict__ adj_w, const float* __restrict__ tevT,
    const float* __restrict__ tevw, float* __restrict__ partials,
    int n, int maxd, int nblk_x)
{
    const int b = blockIdx.y;
    const float* __restrict__ predb = pred + (size_t)b * 3 * n;
    float local = 0.0f;

    for (int v = blockIdx.x * NT + threadIdx.x; v < n; v += nblk_x * NT) {
        const float p0x = predb[v];
        const float p0y = predb[n + v];
        const float p0z = predb[2 * n + v];

        float a00 = 0.f, a01 = 0.f, a02 = 0.f;
        float a10 = 0.f, a11 = 0.f, a12 = 0.f;
        float a20 = 0.f, a21 = 0.f, a22 = 0.f;
        for (int k = 0; k < maxd; ++k) {
            int j = adj_idx[v * maxd + k];
            float ex = predb[j] - p0x;
            float ey = predb[n + j] - p0y;
            float ez = predb[2 * n + j] - p0z;
            const float* tw = tevw + ((size_t)v * maxd + k) * 3;
            float t0 = tw[0], t1 = tw[1], t2 = tw[2];
            a00 += ex * t0; a01 += ex * t1; a02 += ex * t2;
            a10 += ey * t0; a11 += ey * t1; a12 += ey * t2;
            a20 += ez * t0; a21 += ez * t1; a22 += ez * t2;
        }
        const float stab = 1000.0f;
        a00 *= stab; a01 *= stab; a02 *= stab;
        a10 *= stab; a11 *= stab; a12 *= stab;
        a20 *= stab; a21 *= stab; a22 *= stab;

        float m00 = a00 * a00 + a10 * a10 + a20 * a20;
        float m01 = a00 * a01 + a10 * a11 + a20 * a21;
        float m02 = a00 * a02 + a10 * a12 + a20 * a22;
        float m11 = a01 * a01 + a11 * a11 + a21 * a21;
        float m12 = a01 * a02 + a11 * a12 + a21 * a22;
        float m22 = a02 * a02 + a12 * a12 + a22 * a22;

        float v00 = 1.f, v01 = 0.f, v02 = 0.f;
        float v10 = 0.f, v11 = 1.f, v12 = 0.f;
        float v20 = 0.f, v21 = 0.f, v22 = 1.f;
        #pragma unroll
        for (int sweep = 0; sweep < NSWEEPS; ++sweep) {
            jrot(m00, m11, m01, m02, m12, v00, v10, v20, v01, v11, v21);
            jrot(m00, m22, m02, m01, m12, v00, v10, v20, v02, v12, v22);
            jrot(m11, m22, m12, m01, m02, v01, v11, v21, v02, v12, v22);
        }

        float is0 = frsq_(fmaxf(m00, 1e-6f));
        float is1 = frsq_(fmaxf(m11, 1e-6f));
        float is2 = frsq_(fmaxf(m22, 1e-6f));
        float detA = a00 * (a11 * a22 - a21 * a12)
                   - a10 * (a01 * a22 - a21 * a02)
                   + a20 * (a01 * a12 - a11 * a02);
        float dd = detA * is0 * is1 * is2;
        bool c2 = (m22 >= m00) && (m22 >= m11);
        bool c1 = !c2 && (m11 >= m00);
        bool c0 = !c2 && !c1;
        is0 = c0 ? is0 * dd : is0;
        is1 = c1 ? is1 * dd : is1;
        is2 = c2 ? is2 * dd : is2;

        float w00 = is0 * v00 * v00 + is1 * v01 * v01 + is2 * v02 * v02;
        float w01 = is0 * v00 * v10 + is1 * v01 * v11 + is2 * v02 * v12;
        float w02 = is0 * v00 * v20 + is1 * v01 * v21 + is2 * v02 * v22;
        float w11 = is0 * v10 * v10 + is1 * v11 * v11 + is2 * v12 * v12;
        float w12 = is0 * v10 * v20 + is1 * v11 * v21 + is2 * v12 * v22;
        float w22 = is0 * v20 * v20 + is1 * v21 * v21 + is2 * v22 * v22;

        float r00 = a00 * w00 + a01 * w01 + a02 * w02;
        float r01 = a00 * w01 + a01 * w11 + a02 * w12;
        float r02 = a00 * w02 + a01 * w12 + a02 * w22;
        float r10 = a10 * w00 + a11 * w01 + a12 * w02;
        float r11 = a10 * w01 + a11 * w11 + a12 * w12;
        float r12 = a10 * w02 + a11 * w12 + a12 * w22;
        float r20 = a20 * w00 + a21 * w01 + a22 * w02;
        float r21 = a20 * w01 + a21 * w11 + a22 * w12;
        float r22 = a20 * w02 + a21 * w12 + a22 * w22;

        float nrg = 0.0f;
        const float* tvb = tevT + (size_t)v * 3 * maxd;
        for (int k = 0; k < maxd; ++k) {
            int j = adj_idx[v * maxd + k];
            float w = adj_w[v * maxd + k];
            float ex = predb[j] - p0x;
            float ey = predb[n + j] - p0y;
            float ez = predb[2 * n + j] - p0z;
            float tv0 = tvb[k];
            float tv1 = tvb[maxd + k];
            float tv2 = tvb[2 * maxd + k];
            float q0 = r00 * tv0 + r01 * tv1 + r02 * tv2;
            float q1 = r10 * tv0 + r11 * tv1 + r12 * tv2;
            float q2 = r20 * tv0 + r21 * tv1 + r22 * tv2;
            float dx = ex - q0, dy = ey - q1, dz = ez - q2;
            nrg += w * fsqrt_(dx * dx + dy * dy + dz * dz);
        }
        local += fminf(nrg, 1.0f);
    }

    float val = local;
    for (int off = 32; off > 0; off >>= 1)
        val += __shfl_down(val, off, 64);
    __shared__ float smf[NT / 64];
    int lane = threadIdx.x & 63, wid = threadIdx.x >> 6;
    if (lane == 0) smf[wid] = val;
    __syncthreads();
    if (threadIdx.x == 0)
        partials[(size_t)b * nblk_x + blockIdx.x] = smf[0] + smf[1] + smf[2] + smf[3];
}

__global__ __launch_bounds__(NT) void arap_reduce(
    const float* __restrict__ partials, float* __restrict__ out,
    int nblk_x, float inv_n)
{
    int b = blockIdx.x;
    float val = 0.0f;
    for (int i = threadIdx.x; i < nblk_x; i += NT)
        val += partials[(size_t)b * nblk_x + i];
    for (int off = 32; off > 0; off >>= 1)
        val += __shfl_down(val, off, 64);
    __shared__ float smf[NT / 64];
    int lane = threadIdx.x & 63, wid = threadIdx.x >> 6;
    if (lane == 0) smf[wid] = val;
    __syncthreads();
    if (threadIdx.x == 0)
        out[b] = (smf[0] + smf[1] + smf[2] + smf[3]) * inv_n;
}

extern "C" void kernel_launch(void* const* d_in, const int* in_sizes, int n_in,
                              void* d_out, int out_size, void* d_ws, size_t ws_size,
                              hipStream_t stream)
{
    const float* pred    = (const float*)d_in[0];
    const int*   adj_idx = (const int*)d_in[1];
    const float* adj_w   = (const float*)d_in[2];
    const float* tevT    = (const float*)d_in[3];
    const float* tevw    = (const float*)d_in[4];
    float* out = (float*)d_out;

    const int B = 16;
    const int n = in_sizes[0] / (3 * B);
    const int maxd = in_sizes[1] / n;

    int nblk = (n + NT - 1) / NT;
    long long ws_floats = (long long)(ws_size / sizeof(float));
    float* partials = (float*)d_ws;

    if (maxd == 6 && (long long)nblk * B <= ws_floats) {
        dim3 grid(nblk, NBSPLIT);
        arap_fused6<<<grid, NT, 0, stream>>>(pred, adj_idx, adj_w, tevT,
                                             partials, n, nblk);
        arap_reduce<<<B, NT, 0, stream>>>(partials, out, nblk,
                                          1.0f / (float)n);
    } else {
        int nblk_x = nblk;
        if ((long long)nblk_x * B > ws_floats) nblk_x = (int)(ws_floats / B);
        if (nblk_x < 1) nblk_x = 1;
        dim3 grid(nblk_x, B);
        arap_main<<<grid, NT, 0, stream>>>(pred, adj_idx, adj_w, tevT, tevw,
                                           partials, n, maxd, nblk_x);
        arap_reduce<<<B, NT, 0, stream>>>(partials, out, nblk_x,
                                          1.0f / (float)n);
    }
}

// Round 13
// 46.118 us; speedup vs baseline: 26.4810x; 1.0926x over previous
//
#include <hip/hip_runtime.h>
#include <math.h>

#define NT 256
#define NBSPLIT 4
#define NB (16 / NBSPLIT)
#define NSWEEPS 4   // fallback kernel only

__device__ __forceinline__ float fsqrt_(float x) { return __builtin_amdgcn_sqrtf(x); }
__device__ __forceinline__ float frcp_(float x)  { return __builtin_amdgcn_rcpf(x); }
__device__ __forceinline__ float frsq_(float x)  { return __builtin_amdgcn_rsqf(x); }

// maxd==6 specialized: POLAR-NEWTON (in-place, unnormalized) + branchless
// always-on argmax flip (r12 structure, r13 arithmetic cuts).
//   - Frobenius-scaled Newton is SCALE-INVARIANT: mu1 absorbs ||A||, so the
//     X0=A/||A||F normalization is redundant -> iterate in place on A
//     (saves ~28 ops + 9 regs).
//   - 2 scaled + 2 unscaled iterations: kappa<=1e4 -> after 1 scaled iter
//     kappa~1.9, after 2 scaled sigma in [1.001,1.08], two unscaled Newton
//     steps square the error twice -> sigma-err <= 1e-5 << bf16 ulp.
//   - det<0 flip (reference flips LARGEST singular column): v1 = argmax
//     eigvec of M=A^T A via deflated quadratic + rank-1 projector, computed
//     BEFORE Newton (M dies early, only v1+s cross the Newton section),
//     applied branchlessly: X -= s*(X v1) v1^T, s = detA<0 ? 2 : 0.
//     (r10: inline branch = +18us structural; r11: atomics = 23x disaster.)
// Degenerate corners (A~0): NaN -> fminf(NaN,1)=1, error <= 2/n.
// NO launch_bounds min-waves pin (r4/r5: catastrophic spill).
__global__ __launch_bounds__(NT) void arap_fused6(
    const float* __restrict__ pred,      // (B, 3, n)
    const int*   __restrict__ adj_idx,   // (n, 6)
    const float* __restrict__ adj_w,     // (n, 6)
    const float* __restrict__ tevT,      // (n, 3, 6)
    float* __restrict__ partials,        // (B, nblk_x)
    int n, int nblk_x)
{
    __shared__ float tvs[18][NT];        // thread-private column, no barriers
    __shared__ float sm[NT / 64][NB];

    const int tid = threadIdx.x;
    const int v = blockIdx.x * NT + tid;
    const bool active = (v < n);
    const int vc = active ? v : 0;
    const int b0 = blockIdx.y * NB;

    int   jo[6];
    float wgt[6];
    {
        const int2* ai = (const int2*)(adj_idx + (size_t)vc * 6);
        int2 q0 = ai[0], q1 = ai[1], q2 = ai[2];
        jo[0] = q0.x; jo[1] = q0.y; jo[2] = q1.x;
        jo[3] = q1.y; jo[4] = q2.x; jo[5] = q2.y;
        const float2* aw = (const float2*)(adj_w + (size_t)vc * 6);
        float2 w0 = aw[0], w1 = aw[1], w2 = aw[2];
        wgt[0] = w0.x; wgt[1] = w0.y; wgt[2] = w1.x;
        wgt[3] = w1.y; wgt[4] = w2.x; wgt[5] = w2.y;
        const float2* tv = (const float2*)(tevT + (size_t)vc * 18);
        #pragma unroll
        for (int i = 0; i < 9; ++i) {
            float2 t = tv[i];
            tvs[2 * i][tid]     = t.x;
            tvs[2 * i + 1][tid] = t.y;
        }
    }

    const int lane = tid & 63, wid = tid >> 6;

    #pragma unroll 1
    for (int bi = 0; bi < NB; ++bi) {
        const float* __restrict__ predb = pred + (size_t)(b0 + bi) * 3 * n;
        const float p0x = predb[vc];
        const float p0y = predb[n + vc];
        const float p0z = predb[2 * n + vc];

        // Pass 1: gather edges (cached for pass 2); X = A = pred_ev @ (w*tevT^T)
        float ex[6], ey[6], ez[6];
        float x00 = 0.f, x01 = 0.f, x02 = 0.f;
        float x10 = 0.f, x11 = 0.f, x12 = 0.f;
        float x20 = 0.f, x21 = 0.f, x22 = 0.f;
        #pragma unroll
        for (int k = 0; k < 6; ++k) {
            int j = jo[k];
            float exk = predb[j]         - p0x;
            float eyk = predb[n + j]     - p0y;
            float ezk = predb[2 * n + j] - p0z;
            ex[k] = exk; ey[k] = eyk; ez[k] = ezk;
            float t0 = tvs[k][tid], t1 = tvs[6 + k][tid], t2 = tvs[12 + k][tid];
            float w = wgt[k];
            float fx = w * exk, fy = w * eyk, fz = w * ezk;
            x00 += fx * t0; x01 += fx * t1; x02 += fx * t2;
            x10 += fy * t0; x11 += fy * t1; x12 += fy * t2;
            x20 += fz * t0; x21 += fz * t1; x22 += fz * t2;
        }

        float detA = x00 * (x11 * x22 - x21 * x12)
                   - x10 * (x01 * x22 - x21 * x02)
                   + x20 * (x01 * x12 - x11 * x02);

        // ---- hoisted flip precompute: v1 (argmax eigvec of M=A^T A) + s,
        // BEFORE Newton so M dies here; only {v1, s} cross Newton ----
        float vx, vy, vz, s;
        {
            float m00 = x00 * x00 + x10 * x10 + x20 * x20;
            float m01 = x00 * x01 + x10 * x11 + x20 * x21;
            float m02 = x00 * x02 + x10 * x12 + x20 * x22;
            float m11 = x01 * x01 + x11 * x11 + x21 * x21;
            float m12 = x01 * x02 + x11 * x12 + x21 * x22;
            float m22 = x02 * x02 + x12 * x12 + x22 * x22;
            float c2s = m00 + m11 + m22;
            float c1s = m00 * m11 - m01 * m01 + m00 * m22 - m02 * m02
                      + m11 * m22 - m12 * m12;
            float c0s = detA * detA;
            float lam3 = c0s * frcp_(c1s);
            float ch2 = c2s - lam3;
            float ch1 = c1s - lam3 * ch2;
            float disc = fmaxf(ch2 * ch2 - 4.0f * ch1, 0.0f);
            float lam = 0.5f * (ch2 + fsqrt_(disc));
            float sft = c2s - lam;
            float prd = c0s * frcp_(lam);
            float q00 = m00 * m00 + m01 * m01 + m02 * m02 - sft * m00 + prd;
            float q01 = m00 * m01 + m01 * m11 + m02 * m12 - sft * m01;
            float q02 = m00 * m02 + m01 * m12 + m02 * m22 - sft * m02;
            float q11 = m01 * m01 + m11 * m11 + m12 * m12 - sft * m11 + prd;
            float q12 = m01 * m02 + m11 * m12 + m12 * m22 - sft * m12;
            float q22 = m02 * m02 + m12 * m12 + m22 * m22 - sft * m22 + prd;
            if (q00 >= q11 && q00 >= q22)      { vx = q00; vy = q01; vz = q02; }
            else if (q11 >= q22)               { vx = q01; vy = q11; vz = q12; }
            else                               { vx = q02; vy = q12; vz = q22; }
            float inv = frsq_(fmaxf(vx * vx + vy * vy + vz * vz, 1e-30f));
            vx *= inv; vy *= inv; vz *= inv;
            s = (detA < 0.0f) ? 2.0f : 0.0f;
        }

        // ---- scaled Newton, IN PLACE on A (scale-invariant, no X0 norm) ----
        #pragma unroll
        for (int it = 0; it < 2; ++it) {
            float c00 = x11 * x22 - x21 * x12;
            float c01 = x12 * x20 - x10 * x22;
            float c02 = x10 * x21 - x11 * x20;
            float c10 = x02 * x21 - x01 * x22;
            float c11 = x00 * x22 - x02 * x20;
            float c12 = x01 * x20 - x00 * x21;
            float c20 = x01 * x12 - x02 * x11;
            float c21 = x02 * x10 - x00 * x12;
            float c22 = x00 * x11 - x01 * x10;
            float det = x00 * c00 + x01 * c01 + x02 * c02;
            float nX = x00 * x00 + x01 * x01 + x02 * x02
                     + x10 * x10 + x11 * x11 + x12 * x12
                     + x20 * x20 + x21 * x21 + x22 * x22;
            float nC = c00 * c00 + c01 * c01 + c02 * c02
                     + c10 * c10 + c11 * c11 + c12 * c12
                     + c20 * c20 + c21 * c21 + c22 * c22;
            float ratio = nC * frcp_(det * det * nX);
            float mu = fsqrt_(fsqrt_(ratio));
            float f1 = 0.5f * mu;
            float f2 = 0.5f * frcp_(mu * det);
            x00 = f1 * x00 + f2 * c00;
            x01 = f1 * x01 + f2 * c01;
            x02 = f1 * x02 + f2 * c02;
            x10 = f1 * x10 + f2 * c10;
            x11 = f1 * x11 + f2 * c11;
            x12 = f1 * x12 + f2 * c12;
            x20 = f1 * x20 + f2 * c20;
            x21 = f1 * x21 + f2 * c21;
            x22 = f1 * x22 + f2 * c22;
        }
        #pragma unroll
        for (int it = 0; it < 2; ++it) {
            float c00 = x11 * x22 - x21 * x12;
            float c01 = x12 * x20 - x10 * x22;
            float c02 = x10 * x21 - x11 * x20;
            float c10 = x02 * x21 - x01 * x22;
            float c11 = x00 * x22 - x02 * x20;
            float c12 = x01 * x20 - x00 * x21;
            float c20 = x01 * x12 - x02 * x11;
            float c21 = x02 * x10 - x00 * x12;
            float c22 = x00 * x11 - x01 * x10;
            float det = x00 * c00 + x01 * c01 + x02 * c02;
            float f2 = 0.5f * frcp_(det);
            x00 = 0.5f * x00 + f2 * c00;
            x01 = 0.5f * x01 + f2 * c01;
            x02 = 0.5f * x02 + f2 * c02;
            x10 = 0.5f * x10 + f2 * c10;
            x11 = 0.5f * x11 + f2 * c11;
            x12 = 0.5f * x12 + f2 * c12;
            x20 = 0.5f * x20 + f2 * c20;
            x21 = 0.5f * x21 + f2 * c21;
            x22 = 0.5f * x22 + f2 * c22;
        }

        // ---- branchless flip: X -= s * (X v1) v1^T  (s = 0 or 2) ----
        float ux = x00 * vx + x01 * vy + x02 * vz;
        float uy = x10 * vx + x11 * vy + x12 * vz;
        float uz = x20 * vx + x21 * vy + x22 * vz;
        ux *= s; uy *= s; uz *= s;
        x00 -= ux * vx; x01 -= ux * vy; x02 -= ux * vz;
        x10 -= uy * vx; x11 -= uy * vy; x12 -= uy * vz;
        x20 -= uz * vx; x21 -= uz * vy; x22 -= uz * vz;

        // Pass 2: energy from cached edges
        float nrg = 0.0f;
        #pragma unroll
        for (int k = 0; k < 6; ++k) {
            float t0 = tvs[k][tid], t1 = tvs[6 + k][tid], t2 = tvs[12 + k][tid];
            float q0 = x00 * t0 + x01 * t1 + x02 * t2;
            float q1 = x10 * t0 + x11 * t1 + x12 * t2;
            float q2 = x20 * t0 + x21 * t1 + x22 * t2;
            float dx = ex[k] - q0, dy = ey[k] - q1, dz = ez[k] - q2;
            nrg += wgt[k] * fsqrt_(dx * dx + dy * dy + dz * dz);
        }
        float val = active ? fminf(nrg, 1.0f) : 0.0f;

        #pragma unroll
        for (int off = 32; off > 0; off >>= 1)
            val += __shfl_down(val, off, 64);
        if (lane == 0) sm[wid][bi] = val;
    }

    __syncthreads();
    if (tid < NB) {
        float sacc = 0.0f;
        #pragma unroll
        for (int w = 0; w < NT / 64; ++w) sacc += sm[w][tid];
        partials[(size_t)(b0 + tid) * nblk_x + blockIdx.x] = sacc;
    }
}

// ---------------- generic fallback (Jacobi path) ----------------
__device__ __forceinline__ void jrot(float& app, float& aqq, float& apq,
                                     float& arp, float& arq,
                                     float& vp0, float& vp1, float& vp2,
                                     float& vq0, float& vq1, float& vq2)
{
    float a = apq;
    float scale = fabsf(app) + fabsf(aqq);
    if (fabsf(a) > 1e-12f * scale + 1e-35f) {
        float h = aqq - app;
        float r = fsqrt_(fmaf(h, h, 4.0f * a * a));
        float den = fabsf(h) + r;
        float t2a = (h >= 0.0f) ? 2.0f * a : -2.0f * a;
        float t = t2a * frcp_(den);
        float c = frsq_(fmaf(t, t, 1.0f));
        float s = t * c;
        app -= t * a;
        aqq += t * a;
        apq = 0.0f;
        float rp = arp, rq = arq;
        arp = c * rp - s * rq;
        arq = s * rp + c * rq;
        float x, y;
        x = vp0; y = vq0; vp0 = c * x - s * y; vq0 = s * x + c * y;
        x = vp1; y = vq1; vp1 = c * x - s * y; vq1 = s * x + c * y;
        x = vp2; y = vq2; vp2 = c * x - s * y; vq2 = s * x + c * y;
    }
}

__global__ __launch_bounds__(NT) void arap_main(
    const float* __restrict__ pred, const int* __restrict__ adj_idx,
    const float* __restrict__ adj_w, const float* __restrict__ tevT,
    const float* __restrict__ tevw, float* __restrict__ partials,
    int n, int maxd, int nblk_x)
{
    const int b = blockIdx.y;
    const float* __restrict__ predb = pred + (size_t)b * 3 * n;
    float local = 0.0f;

    for (int v = blockIdx.x * NT + threadIdx.x; v < n; v += nblk_x * NT) {
        const float p0x = predb[v];
        const float p0y = predb[n + v];
        const float p0z = predb[2 * n + v];

        float a00 = 0.f, a01 = 0.f, a02 = 0.f;
        float a10 = 0.f, a11 = 0.f, a12 = 0.f;
        float a20 = 0.f, a21 = 0.f, a22 = 0.f;
        for (int k = 0; k < maxd; ++k) {
            int j = adj_idx[v * maxd + k];
            float ex = predb[j] - p0x;
            float ey = predb[n + j] - p0y;
            float ez = predb[2 * n + j] - p0z;
            const float* tw = tevw + ((size_t)v * maxd + k) * 3;
            float t0 = tw[0], t1 = tw[1], t2 = tw[2];
            a00 += ex * t0; a01 += ex * t1; a02 += ex * t2;
            a10 += ey * t0; a11 += ey * t1; a12 += ey * t2;
            a20 += ez * t0; a21 += ez * t1; a22 += ez * t2;
        }
        const float stab = 1000.0f;
        a00 *= stab; a01 *= stab; a02 *= stab;
        a10 *= stab; a11 *= stab; a12 *= stab;
        a20 *= stab; a21 *= stab; a22 *= stab;

        float m00 = a00 * a00 + a10 * a10 + a20 * a20;
        float m01 = a00 * a01 + a10 * a11 + a20 * a21;
        float m02 = a00 * a02 + a10 * a12 + a20 * a22;
        float m11 = a01 * a01 + a11 * a11 + a21 * a21;
        float m12 = a01 * a02 + a11 * a12 + a21 * a22;
        float m22 = a02 * a02 + a12 * a12 + a22 * a22;

        float v00 = 1.f, v01 = 0.f, v02 = 0.f;
        float v10 = 0.f, v11 = 1.f, v12 = 0.f;
        float v20 = 0.f, v21 = 0.f, v22 = 1.f;
        #pragma unroll
        for (int sweep = 0; sweep < NSWEEPS; ++sweep) {
            jrot(m00, m11, m01, m02, m12, v00, v10, v20, v01, v11, v21);
            jrot(m00, m22, m02, m01, m12, v00, v10, v20, v02, v12, v22);
            jrot(m11, m22, m12, m01, m02, v01, v11, v21, v02, v12, v22);
        }

        float is0 = frsq_(fmaxf(m00, 1e-6f));
        float is1 = frsq_(fmaxf(m11, 1e-6f));
        float is2 = frsq_(fmaxf(m22, 1e-6f));
        float detA = a00 * (a11 * a22 - a21 * a12)
                   - a10 * (a01 * a22 - a21 * a02)
                   + a20 * (a01 * a12 - a11 * a02);
        float dd = detA * is0 * is1 * is2;
        bool c2 = (m22 >= m00) && (m22 >= m11);
        bool c1 = !c2 && (m11 >= m00);
        bool c0 = !c2 && !c1;
        is0 = c0 ? is0 * dd : is0;
        is1 = c1 ? is1 * dd : is1;
        is2 = c2 ? is2 * dd : is2;

        float w00 = is0 * v00 * v00 + is1 * v01 * v01 + is2 * v02 * v02;
        float w01 = is0 * v00 * v10 + is1 * v01 * v11 + is2 * v02 * v12;
        float w02 = is0 * v00 * v20 + is1 * v01 * v21 + is2 * v02 * v22;
        float w11 = is0 * v10 * v10 + is1 * v11 * v11 + is2 * v12 * v12;
        float w12 = is0 * v10 * v20 + is1 * v11 * v21 + is2 * v12 * v22;
        float w22 = is0 * v20 * v20 + is1 * v21 * v21 + is2 * v22 * v22;

        float r00 = a00 * w00 + a01 * w01 + a02 * w02;
        float r01 = a00 * w01 + a01 * w11 + a02 * w12;
        float r02 = a00 * w02 + a01 * w12 + a02 * w22;
        float r10 = a10 * w00 + a11 * w01 + a12 * w02;
        float r11 = a10 * w01 + a11 * w11 + a12 * w12;
        float r12 = a10 * w02 + a11 * w12 + a12 * w22;
        float r20 = a20 * w00 + a21 * w01 + a22 * w02;
        float r21 = a20 * w01 + a21 * w11 + a22 * w12;
        float r22 = a20 * w02 + a21 * w12 + a22 * w22;

        float nrg = 0.0f;
        const float* tvb = tevT + (size_t)v * 3 * maxd;
        for (int k = 0; k < maxd; ++k) {
            int j = adj_idx[v * maxd + k];
            float w = adj_w[v * maxd + k];
            float ex = predb[j] - p0x;
            float ey = predb[n + j] - p0y;
            float ez = predb[2 * n + j] - p0z;
            float tv0 = tvb[k];
            float tv1 = tvb[maxd + k];
            float tv2 = tvb[2 * maxd + k];
            float q0 = r00 * tv0 + r01 * tv1 + r02 * tv2;
            float q1 = r10 * tv0 + r11 * tv1 + r12 * tv2;
            float q2 = r20 * tv0 + r21 * tv1 + r22 * tv2;
            float dx = ex - q0, dy = ey - q1, dz = ez - q2;
            nrg += w * fsqrt_(dx * dx + dy * dy + dz * dz);
        }
        local += fminf(nrg, 1.0f);
    }

    float val = local;
    for (int off = 32; off > 0; off >>= 1)
        val += __shfl_down(val, off, 64);
    __shared__ float smf[NT / 64];
    int lane = threadIdx.x & 63, wid = threadIdx.x >> 6;
    if (lane == 0) smf[wid] = val;
    __syncthreads();
    if (threadIdx.x == 0)
        partials[(size_t)b * nblk_x + blockIdx.x] = smf[0] + smf[1] + smf[2] + smf[3];
}

__global__ __launch_bounds__(NT) void arap_reduce(
    const float* __restrict__ partials, float* __restrict__ out,
    int nblk_x, float inv_n)
{
    int b = blockIdx.x;
    float val = 0.0f;
    for (int i = threadIdx.x; i < nblk_x; i += NT)
        val += partials[(size_t)b * nblk_x + i];
    for (int off = 32; off > 0; off >>= 1)
        val += __shfl_down(val, off, 64);
    __shared__ float smf[NT / 64];
    int lane = threadIdx.x & 63, wid = threadIdx.x >> 6;
    if (lane == 0) smf[wid] = val;
    __syncthreads();
    if (threadIdx.x == 0)
        out[b] = (smf[0] + smf[1] + smf[2] + smf[3]) * inv_n;
}

extern "C" void kernel_launch(void* const* d_in, const int* in_sizes, int n_in,
                              void* d_out, int out_size, void* d_ws, size_t ws_size,
                              hipStream_t stream)
{
    const float* pred    = (const float*)d_in[0];
    const int*   adj_idx = (const int*)d_in[1];
    const float* adj_w   = (const float*)d_in[2];
    const float* tevT    = (const float*)d_in[3];
    const float* tevw    = (const float*)d_in[4];
    float* out = (float*)d_out;

    const int B = 16;
    const int n = in_sizes[0] / (3 * B);
    const int maxd = in_sizes[1] / n;

    int nblk = (n + NT - 1) / NT;
    long long ws_floats = (long long)(ws_size / sizeof(float));
    float* partials = (float*)d_ws;

    if (maxd == 6 && (long long)nblk * B <= ws_floats) {
        dim3 grid(nblk, NBSPLIT);
        arap_fused6<<<grid, NT, 0, stream>>>(pred, adj_idx, adj_w, tevT,
                                             partials, n, nblk);
        arap_reduce<<<B, NT, 0, stream>>>(partials, out, nblk,
                                          1.0f / (float)n);
    } else {
        int nblk_x = nblk;
        if ((long long)nblk_x * B > ws_floats) nblk_x = (int)(ws_floats / B);
        if (nblk_x < 1) nblk_x = 1;
        dim3 grid(nblk_x, B);
        arap_main<<<grid, NT, 0, stream>>>(pred, adj_idx, adj_w, tevT, tevw,
                                           partials, n, maxd, nblk_x);
        arap_reduce<<<B, NT, 0, stream>>>(partials, out, nblk_x,
                                          1.0f / (float)n);
    }
}